// Round 12
// baseline (383.060 us; speedup 1.0000x reference)
//
#include <hip/hip_runtime.h>

// B=2, S=4096, D=768, H=12, HD=64
#define Sq 4096
#define Dm 768
#define Hh 12
#define KD 768

typedef short short8 __attribute__((ext_vector_type(8)));
typedef float f32x4 __attribute__((ext_vector_type(4)));
typedef unsigned short bf_t;

__device__ inline bf_t f2bf(float f) {
    unsigned int u = __builtin_bit_cast(unsigned int, f);
    u += 0x7fffu + ((u >> 16) & 1u);   // RNE
    return (bf_t)(u >> 16);
}

// pack two fp32 -> bf16x2 (round-half-up: 1 add each + 1 v_perm) — HW-verified path
__device__ inline unsigned int pk2bf(float a, float b) {
    unsigned int ua = __builtin_bit_cast(unsigned int, a) + 0x8000u;
    unsigned int ub = __builtin_bit_cast(unsigned int, b) + 0x8000u;
    return __builtin_amdgcn_perm(ub, ua, 0x07060302);
}

__device__ inline float fexp2(float x) {
#if __has_builtin(__builtin_amdgcn_exp2f)
    return __builtin_amdgcn_exp2f(x);
#else
    return exp2f(x);
#endif
}

__device__ inline void gl_lds16(const void* g, void* l) {
    __builtin_amdgcn_global_load_lds(
        (const __attribute__((address_space(1))) unsigned int*)g,
        (__attribute__((address_space(3))) unsigned int*)l, 16, 0, 0);
}

// ---------------- fp32 -> bf16 convert, up to 8 arrays per launch ----------------
struct CvtJobs { const float* s[8]; bf_t* d[8]; int n[8]; };

__global__ __launch_bounds__(256) void cvt(CvtJobs jobs) {
    const float* s = jobs.s[blockIdx.z];
    bf_t* d = jobs.d[blockIdx.z];
    int n = jobs.n[blockIdx.z];
    int i = (blockIdx.x * 256 + threadIdx.x) * 8;
    if (i < n) {
        float4 a = *(const float4*)(s + i);
        float4 b = *(const float4*)(s + i + 4);
        short8 p;
        p[0] = (short)f2bf(a.x); p[1] = (short)f2bf(a.y);
        p[2] = (short)f2bf(a.z); p[3] = (short)f2bf(a.w);
        p[4] = (short)f2bf(b.x); p[5] = (short)f2bf(b.y);
        p[6] = (short)f2bf(b.z); p[7] = (short)f2bf(b.w);
        *(short8*)(d + i) = p;
    }
}

// ---------------- bf16 GEMM: C = A (MxK) * B^T (NxK) + bias ----------------
// mode 0: Q -> standard [bh][s][64] (scaled)
// mode 3: K -> FRAGMENT-PACKED [bh][kt][t][half][lane][8]
// mode 1: V -> FRAGMENT-PACKED [bh][kt][g*4+ot][lane][8]
// mode 2: fp32 out [row][Dm]
struct GemmJob {
    const bf_t* __restrict__ A; const bf_t* __restrict__ Bm;
    const float* __restrict__ bias; void* __restrict__ out;
    int mode; float scale;
};
struct GemmJobs { GemmJob j[3]; };

__global__ __launch_bounds__(256) void gemm_k(GemmJobs jobs) {
    const GemmJob J = jobs.j[blockIdx.z];
    __shared__ bf_t As[128 * 64];
    __shared__ bf_t Bs[128 * 64];
    const int lane = threadIdx.x & 63, wv = threadIdx.x >> 6;
    const int l16 = lane & 15, quad = lane >> 4;
    const int wm = wv >> 1, wn = wv & 1;
    int m0, n0;
    if (J.mode == 1) { m0 = blockIdx.y * 128; n0 = blockIdx.x * 128; }
    else             { m0 = blockIdx.x * 128; n0 = blockIdx.y * 128; }

    f32x4 acc[4][4] = {};

    for (int kk = 0; kk < KD; kk += 64) {
#pragma unroll
        for (int it = 0; it < 4; ++it) {
            int p0 = it * 256 + wv * 64;
            int p = p0 + lane;
            int row = p >> 3;
            int c = (p & 7) ^ (row & 7);
            gl_lds16(J.A + (size_t)(m0 + row) * KD + kk + c * 8, As + p0 * 8);
            gl_lds16(J.Bm + (size_t)(n0 + row) * KD + kk + c * 8, Bs + p0 * 8);
        }
        __syncthreads();
#pragma unroll
        for (int ks = 0; ks < 2; ++ks) {
            short8 a[4], b[4];
#pragma unroll
            for (int i = 0; i < 4; ++i) {
                int row = wm * 64 + i * 16 + l16;
                int pc = (ks * 4 + quad) ^ (row & 7);
                a[i] = *(const short8*)&As[row * 64 + pc * 8];
            }
#pragma unroll
            for (int j = 0; j < 4; ++j) {
                int row = wn * 64 + j * 16 + l16;
                int pc = (ks * 4 + quad) ^ (row & 7);
                b[j] = *(const short8*)&Bs[row * 64 + pc * 8];
            }
#pragma unroll
            for (int i = 0; i < 4; ++i)
#pragma unroll
                for (int j = 0; j < 4; ++j)
                    acc[i][j] = __builtin_amdgcn_mfma_f32_16x16x32_bf16(a[i], b[j], acc[i][j], 0, 0, 0);
        }
        __syncthreads();
    }

#pragma unroll
    for (int i = 0; i < 4; ++i) {
#pragma unroll
        for (int j = 0; j < 4; ++j) {
            int grow = m0 + wm * 64 + i * 16 + quad * 4;
            int gcol = n0 + wn * 64 + j * 16 + l16;
            if (J.mode == 0) {
                float bv = J.bias[gcol];
                int h = gcol >> 6, hd = gcol & 63;
                bf_t* dst = (bf_t*)J.out;
#pragma unroll
                for (int r = 0; r < 4; ++r) {
                    int row = grow + r;
                    int bI = row >> 12, s = row & 4095;
                    dst[(((size_t)(bI * Hh + h) * Sq + s) << 6) + hd] =
                        f2bf((acc[i][j][r] + bv) * J.scale);
                }
            } else if (J.mode == 3) {
                // K fragment-packed: [bh][kt][t=2g+s2][h2][lane][8]
                float bv = J.bias[gcol];
                int hh = gcol >> 6, hd = gcol & 63;
                int h2 = hd >> 5, rem = hd & 31, qd = rem >> 3, j2 = rem & 7;
                bf_t* dst = (bf_t*)J.out;
#pragma unroll
                for (int r = 0; r < 4; ++r) {
                    int row = grow + r;
                    int bI = row >> 12, s = row & 4095;
                    int kt2 = s >> 6, rr = s & 63;
                    int g2 = rr >> 5, r5 = rr & 31;
                    int a2 = r5 >> 3, s22 = (r5 >> 2) & 1, b2 = r5 & 3;
                    int lane2 = qd * 16 + (4 * a2 + b2);
                    dst[(size_t)(bI * Hh + hh) * Sq * 64 +
                        kt2 * 4096 + (2 * g2 + s22) * 1024 + h2 * 512 + lane2 * 8 + j2] =
                        f2bf(acc[i][j][r] + bv);
                }
            } else if (J.mode == 1) {
                // V fragment-packed: [bh][kt][g*4+ot][lane][8]
                bf_t* dst = (bf_t*)J.out;
                int t = gcol, bI = t >> 12, s = t & 4095;
                int kt2 = s >> 6, rr = s & 63;
                int g2 = rr >> 5, qd = (rr & 31) >> 3, j2 = rr & 7;
#pragma unroll
                for (int r = 0; r < 4; ++r) {
                    int f = grow + r;
                    int hh = f >> 6, hd = f & 63;
                    int ot = hd >> 4, l16v = hd & 15;
                    int lane2 = qd * 16 + l16v;
                    dst[(size_t)(bI * Hh + hh) * Sq * 64 +
                        kt2 * 4096 + (g2 * 4 + ot) * 512 + lane2 * 8 + j2] =
                        f2bf(acc[i][j][r] + J.bias[f]);
                }
            } else {
                float bv = J.bias[gcol];
                float* dst = (float*)J.out;
#pragma unroll
                for (int r = 0; r < 4; ++r)
                    dst[(size_t)(grow + r) * Dm + gcol] = acc[i][j][r] + bv;
            }
        }
    }
}

// ---------------- flash attention, causal, fixed-shift softmax ----------------
// Q: [B*H, S, 64] bf16 (pre-scaled by (1/8)*log2e). K/VT: FRAGMENT-PACKED
// (gemm modes 3/1) -> every K/V load is a coalesced lane*16B burst.
// BALANCED-PAIR version (R11 post-mortem: latency-bound, avg 0.8 waves/SIMD
// vs 3/SIMD cap; 1:32 block imbalance starves the tail; R7 balance failed by
// breaking 2-way L1 sharing + residency, both preserved here):
//   grid (24, 16); block = R6's 4 waves {rg x ksp}; SEGMENT A (qt = 31-y)
//   then SEGMENT B (qt = y). Per-wave tiles = 32+rg, CONSTANT grid-wide ->
//   1536 equal waves sustain ~1.5 waves/SIMD for the whole run.
// Per-segment body/combine bit-identical to the verified R6/R7/R11 pieces.
// XCD swizzle: 384 = 8*48; each XCD owns 3 heads.
// NOTE: no min-occupancy arg in __launch_bounds__ (R3: (256,4) forced a
// 64-VGPR cap -> 2.3GB scratch spill).
#define SHIFT 18.0f
#define NQ 4

__global__ __launch_bounds__(256) void attn(const bf_t* __restrict__ Q,
                                            const bf_t* __restrict__ K,
                                            const bf_t* __restrict__ VT,
                                            bf_t* __restrict__ O) {
    const int id = blockIdx.x + 24 * blockIdx.y;   // grid (24,16) -> 0..383
    const int xcd = id & 7, slot = id >> 3;        // slot 0..47
    const int bh = xcd * 3 + slot % 3;
    const int y = slot / 3;                        // 0..15
    const int lane = threadIdx.x & 63, wv = threadIdx.x >> 6;   // wv 0..3
    const int rg = wv & 1, ksp = wv >> 1;          // row-group, key-split
    const int l16 = lane & 15, quad = lane >> 4;
    const int b = bh / Hh, h = bh % Hh;
    const size_t base = (size_t)bh * Sq * 64;

    __shared__ float ocomb[2][64][68];             // [rg][row][feat] fp32, padded
    __shared__ float lcomb[2][64];

    const bf_t* __restrict__ Kb = K + base;
    const bf_t* __restrict__ Vb = VT + base;

    short8 ones32;
#pragma unroll
    for (int j = 0; j < 8; ++j) ones32[j] = (short)0x3F80;

    short8 qf[NQ][2];
    f32x4 oacc[NQ][4];
    f32x4 lsum[NQ];
    short8 kf[4][2];   // K frags (packed layout), t=2g+s
    short8 vfr[4][2];  // V frags [ot][g]

#define LOAD_K()                                                             \
    {                                                                        \
        _Pragma("unroll")                                                    \
        for (int t = 0; t < 4; ++t) {                                        \
            kf[t][0] = *(const short8*)(Kb + ko + t * 1024);                 \
            kf[t][1] = *(const short8*)(Kb + ko + t * 1024 + 512);           \
        }                                                                    \
    }
#define LOAD_V()                                                             \
    {                                                                        \
        _Pragma("unroll")                                                    \
        for (int ot = 0; ot < 4; ++ot)                                       \
            _Pragma("unroll")                                                \
            for (int g = 0; g < 2; ++g)                                      \
                vfr[ot][g] = *(const short8*)(Vb + vo + (g * 4 + ot) * 512); \
    }

    for (int seg = 0; seg < 2; ++seg) {
        const int qt = seg ? y : 31 - y;           // long segment first
        const int q0 = qt * 128 + rg * 64;

        // Q as B-frags (n=qrow l16, k=quad*8+j)
#pragma unroll
        for (int i = 0; i < NQ; ++i) {
            const bf_t* qp = Q + base + (size_t)(q0 + i * 16 + l16) * 64 + quad * 8;
            qf[i][0] = *(const short8*)qp;
            qf[i][1] = *(const short8*)(qp + 32);
            lsum[i] = (f32x4){};
#pragma unroll
            for (int ot = 0; ot < 4; ++ot) oacc[i][ot] = (f32x4){};
        }

        const int nkt = (q0 >> 6) + 1;
        const int hsp = (nkt + 1) >> 1;
        const int kt0 = ksp ? hsp : 0;
        const int kt1 = ksp ? nkt : hsp;

        int ko = kt0 * 4096 + lane * 8;
        int vo = kt0 * 4096 + lane * 8;

        if (kt0 < kt1) { LOAD_K(); LOAD_V(); }

        for (int kt = kt0; kt < kt1; ++kt) {
            const int kv0 = kt * 64;
            const bool more = (kt + 1 < kt1);
#pragma unroll
            for (int i = 0; i < NQ; ++i) {
                // QK: S^T tiles, permuted key order; C-init carries the -SHIFT
                f32x4 st[4];
#pragma unroll
                for (int t = 0; t < 4; ++t) {
                    f32x4 z = {-SHIFT, -SHIFT, -SHIFT, -SHIFT};
                    z = __builtin_amdgcn_mfma_f32_16x16x32_bf16(kf[t][0], qf[i][0], z, 0, 0, 0);
                    st[t] = __builtin_amdgcn_mfma_f32_16x16x32_bf16(kf[t][1], qf[i][1], z, 0, 0, 0);
                }
                if (i == NQ - 1) { ko += 4096; if (more) LOAD_K(); }   // WAR prefetch

                // mask + exp2 + pack (permuted key = kv0+32g+8*quad+4s+r)
                alignas(16) unsigned int pkd[4][2];
                const bool need_mask = (kv0 + 63 > q0 + i * 16);
#pragma unroll
                for (int t = 0; t < 4; ++t) {
                    int g = t >> 1, s = t & 1;
                    f32x4 sv = st[t];
                    if (need_mask) {
                        int qrow = q0 + i * 16 + l16;
                        int kb2 = kv0 + 32 * g + 8 * quad + 4 * s;
#pragma unroll
                        for (int r = 0; r < 4; ++r)
                            if (kb2 + r > qrow) sv[r] = -1e30f;
                    }
                    pkd[t][0] = pk2bf(fexp2(sv[0]), fexp2(sv[1]));
                    pkd[t][1] = pk2bf(fexp2(sv[2]), fexp2(sv[3]));
                }
                // PV: B-frag direct from pkd, K=32
#pragma unroll
                for (int g = 0; g < 2; ++g) {
                    short8 pf = *(const short8*)&pkd[2 * g][0];
                    lsum[i] = __builtin_amdgcn_mfma_f32_16x16x32_bf16(ones32, pf, lsum[i], 0, 0, 0);
#pragma unroll
                    for (int ot = 0; ot < 4; ++ot)
                        oacc[i][ot] = __builtin_amdgcn_mfma_f32_16x16x32_bf16(vfr[ot][g], pf, oacc[i][ot], 0, 0, 0);
                }
            }
            vo += 4096;
            if (more) LOAD_V();   // WAR prefetch
        }

        // combine partials: split-1 writes, barrier, split-0 adds + epilogue
        if (ksp) {
#pragma unroll
            for (int i = 0; i < NQ; ++i) {
                int row = i * 16 + l16;
#pragma unroll
                for (int ot = 0; ot < 4; ++ot)
                    *(f32x4*)&ocomb[rg][row][ot * 16 + quad * 4] = oacc[i][ot];
                if (quad == 0) lcomb[rg][row] = lsum[i][0];
            }
        }
        __syncthreads();
        if (!ksp) {
#pragma unroll
            for (int i = 0; i < NQ; ++i) {
                int row = i * 16 + l16;
                float ls = lsum[i][0] + lcomb[rg][row];
                float inv = 1.0f / ls;
                int srow = q0 + row;
                bf_t* orow = O + (size_t)(b * Sq + srow) * Dm + h * 64;
#pragma unroll
                for (int ot = 0; ot < 4; ++ot) {
                    f32x4 oc = *(const f32x4*)&ocomb[rg][row][ot * 16 + quad * 4];
                    uint2 pk;
                    pk.x = pk2bf((oacc[i][ot][0] + oc[0]) * inv, (oacc[i][ot][1] + oc[1]) * inv);
                    pk.y = pk2bf((oacc[i][ot][2] + oc[2]) * inv, (oacc[i][ot][3] + oc[3]) * inv);
                    *(uint2*)(orow + ot * 16 + quad * 4) = pk;
                }
            }
        }
        if (seg == 0) __syncthreads();   // guard ocomb reuse before segment B writers
    }
#undef LOAD_K
#undef LOAD_V
}

extern "C" void kernel_launch(void* const* d_in, const int* in_sizes, int n_in,
                              void* d_out, int out_size, void* d_ws, size_t ws_size,
                              hipStream_t stream) {
    const float* q  = (const float*)d_in[0];
    const float* k  = (const float*)d_in[1];
    const float* v  = (const float*)d_in[2];
    // d_in[3]: causal mask — analytic
    const float* Wq = (const float*)d_in[4];  const float* bq = (const float*)d_in[5];
    const float* Wk = (const float*)d_in[6];  const float* bk = (const float*)d_in[7];
    const float* Wv = (const float*)d_in[8];  const float* bv = (const float*)d_in[9];
    const float* Wo = (const float*)d_in[10]; const float* bo = (const float*)d_in[11];
    float* out = (float*)d_out;

    const float QSCALE = 0.125f * 1.44269504f;     // (1/sqrt(64)) * log2(e)

    const size_t NTOK = (size_t)2 * Sq * Dm;   // 6291456
    const size_t NW   = (size_t)Dm * Dm;       // 589824
    dim3 b256(256);

    const size_t need_main = (6 * NTOK + 4 * NW) * 2;   // 80.2 MB

    if (ws_size >= need_main) {
        bf_t* qb  = (bf_t*)d_ws;
        bf_t* kb  = qb + NTOK;
        bf_t* vb  = kb + NTOK;
        bf_t* xq  = vb + NTOK;
        bf_t* xk  = xq + NTOK;
        bf_t* xv  = xk + NTOK;
        bf_t* wqb = xv + NTOK;
        bf_t* wkb = wqb + NW;
        bf_t* wvb = wkb + NW;
        bf_t* wob = wvb + NW;
        bf_t* ob  = xq;

        // one merged cvt launch: 3 big input jobs + 4 small weight jobs
        CvtJobs cj = {{q, k, v, Wq, Wk, Wv, Wo, q},
                      {xq, xk, xv, wqb, wkb, wvb, wob, xq},
                      {(int)NTOK, (int)NTOK, (int)NTOK,
                       (int)NW, (int)NW, (int)NW, (int)NW, 0}};
        cvt<<<dim3(3072, 1, 7), b256, 0, stream>>>(cj);

        GemmJobs gp;
        gp.j[0] = {xq,  wqb, bq, qb, 0, QSCALE};
        gp.j[1] = {xk,  wkb, bk, kb, 3, 1.0f};     // K fragment-packed
        gp.j[2] = {wvb, xv,  bv, vb, 1, 1.0f};     // V fragment-packed
        gemm_k<<<dim3(64, 6, 3), b256, 0, stream>>>(gp);

        attn<<<dim3(2 * Hh, 16), b256, 0, stream>>>(qb, kb, vb, ob);

        GemmJobs go;
        go.j[0] = {ob, wob, bo, out, 2, 1.0f};
        go.j[1] = go.j[0]; go.j[2] = go.j[0];
        gemm_k<<<dim3(64, 6, 1), b256, 0, stream>>>(go);
    } else {
        bf_t* qb  = (bf_t*)d_ws;
        bf_t* kb  = qb + NTOK;
        bf_t* vb  = kb + NTOK;
        bf_t* ob  = vb + NTOK;
        bf_t* xc  = ob + NTOK;
        bf_t* wqb = xc + NTOK;
        bf_t* wkb = wqb + NW;
        bf_t* wvb = wkb + NW;
        bf_t* wob = wvb + NW;

        CvtJobs cw = {{Wq, Wk, Wv, Wo, Wq, Wq, Wq, Wq},
                      {wqb, wkb, wvb, wob, wqb, wqb, wqb, wqb},
                      {(int)NW, (int)NW, (int)NW, (int)NW, 0, 0, 0, 0}};
        cvt<<<dim3(288, 1, 4), b256, 0, stream>>>(cw);

        GemmJobs gj;
        CvtJobs c1 = {{q}, {xc}, {(int)NTOK}};
        cvt<<<dim3(3072, 1, 1), b256, 0, stream>>>(c1);
        gj.j[0] = {xc, wqb, bq, qb, 0, QSCALE}; gj.j[1] = gj.j[0]; gj.j[2] = gj.j[0];
        gemm_k<<<dim3(64, 6, 1), b256, 0, stream>>>(gj);

        CvtJobs c2 = {{k}, {xc}, {(int)NTOK}};
        cvt<<<dim3(3072, 1, 1), b256, 0, stream>>>(c2);
        gj.j[0] = {xc, wkb, bk, kb, 3, 1.0f}; gj.j[1] = gj.j[0]; gj.j[2] = gj.j[0];
        gemm_k<<<dim3(64, 6, 1), b256, 0, stream>>>(gj);

        CvtJobs c3 = {{v}, {xc}, {(int)NTOK}};
        cvt<<<dim3(3072, 1, 1), b256, 0, stream>>>(c3);
        gj.j[0] = {wvb, xc, bv, vb, 1, 1.0f}; gj.j[1] = gj.j[0]; gj.j[2] = gj.j[0];
        gemm_k<<<dim3(64, 6, 1), b256, 0, stream>>>(gj);

        attn<<<dim3(2 * Hh, 16), b256, 0, stream>>>(qb, kb, vb, ob);

        gj.j[0] = {ob, wob, bo, out, 2, 1.0f}; gj.j[1] = gj.j[0]; gj.j[2] = gj.j[0];
        gemm_k<<<dim3(64, 6, 1), b256, 0, stream>>>(gj);
    }
}

// Round 13
// 358.800 us; speedup vs baseline: 1.0676x; 1.0676x over previous
//
#include <hip/hip_runtime.h>

// B=2, S=4096, D=768, H=12, HD=64
#define Sq 4096
#define Dm 768
#define Hh 12
#define KD 768

typedef short short8 __attribute__((ext_vector_type(8)));
typedef float f32x4 __attribute__((ext_vector_type(4)));
typedef unsigned short bf_t;

__device__ inline bf_t f2bf(float f) {
    unsigned int u = __builtin_bit_cast(unsigned int, f);
    u += 0x7fffu + ((u >> 16) & 1u);   // RNE
    return (bf_t)(u >> 16);
}

// pack two fp32 -> bf16x2 (round-half-up: 1 add each + 1 v_perm) — HW-verified path
__device__ inline unsigned int pk2bf(float a, float b) {
    unsigned int ua = __builtin_bit_cast(unsigned int, a) + 0x8000u;
    unsigned int ub = __builtin_bit_cast(unsigned int, b) + 0x8000u;
    return __builtin_amdgcn_perm(ub, ua, 0x07060302);
}

__device__ inline float fexp2(float x) {
#if __has_builtin(__builtin_amdgcn_exp2f)
    return __builtin_amdgcn_exp2f(x);
#else
    return exp2f(x);
#endif
}

__device__ inline void gl_lds16(const void* g, void* l) {
    __builtin_amdgcn_global_load_lds(
        (const __attribute__((address_space(1))) unsigned int*)g,
        (__attribute__((address_space(3))) unsigned int*)l, 16, 0, 0);
}

// ---------------- fp32 -> bf16 convert (weights only now) ----------------
struct CvtJobs { const float* s[8]; bf_t* d[8]; int n[8]; };

__global__ __launch_bounds__(256) void cvt(CvtJobs jobs) {
    const float* s = jobs.s[blockIdx.z];
    bf_t* d = jobs.d[blockIdx.z];
    int n = jobs.n[blockIdx.z];
    int i = (blockIdx.x * 256 + threadIdx.x) * 8;
    if (i < n) {
        float4 a = *(const float4*)(s + i);
        float4 b = *(const float4*)(s + i + 4);
        short8 p;
        p[0] = (short)f2bf(a.x); p[1] = (short)f2bf(a.y);
        p[2] = (short)f2bf(a.z); p[3] = (short)f2bf(a.w);
        p[4] = (short)f2bf(b.x); p[5] = (short)f2bf(b.y);
        p[6] = (short)f2bf(b.z); p[7] = (short)f2bf(b.w);
        *(short8*)(d + i) = p;
    }
}

// ---------------- bf16 GEMM: C = A (MxK) * B^T (NxK) + bias ----------------
// a32=1: A is fp32 — conversion FUSED into staging (reg-stage + ds_write),
//        eliminating the separate input-cvt round trip (R13).
// mode 0: Q -> standard [bh][s][64] (scaled)
// mode 3: K -> FRAGMENT-PACKED [bh][kt][t][half][lane][8] (A=tokens)
// mode 4: V -> FRAGMENT-PACKED [bh][kt][g*4+ot][lane][8] (A=tokens; same
//         slot algebra as the R11-verified mode 1, transposed source)
// mode 2: fp32 out [row][Dm]
struct GemmJob {
    const void* __restrict__ A; const bf_t* __restrict__ Bm;
    const float* __restrict__ bias; void* __restrict__ out;
    int mode; float scale; int a32;
};
struct GemmJobs { GemmJob j[3]; };

__global__ __launch_bounds__(256) void gemm_k(GemmJobs jobs) {
    const GemmJob J = jobs.j[blockIdx.z];
    __shared__ bf_t As[128 * 64];
    __shared__ bf_t Bs[128 * 64];
    const int lane = threadIdx.x & 63, wv = threadIdx.x >> 6;
    const int l16 = lane & 15, quad = lane >> 4;
    const int wm = wv >> 1, wn = wv & 1;
    const int m0 = blockIdx.x * 128, n0 = blockIdx.y * 128;

    f32x4 acc[4][4] = {};

    for (int kk = 0; kk < KD; kk += 64) {
        if (J.a32) {
            const float* A32 = (const float*)J.A;
#pragma unroll
            for (int it = 0; it < 4; ++it) {
                int p0 = it * 256 + wv * 64;
                int p = p0 + lane;
                int row = p >> 3;
                int c = (p & 7) ^ (row & 7);
                const float* src = A32 + (size_t)(m0 + row) * KD + kk + c * 8;
                float4 a0 = *(const float4*)src;
                float4 a1 = *(const float4*)(src + 4);
                short8 pp;
                pp[0] = (short)f2bf(a0.x); pp[1] = (short)f2bf(a0.y);
                pp[2] = (short)f2bf(a0.z); pp[3] = (short)f2bf(a0.w);
                pp[4] = (short)f2bf(a1.x); pp[5] = (short)f2bf(a1.y);
                pp[6] = (short)f2bf(a1.z); pp[7] = (short)f2bf(a1.w);
                *(short8*)&As[p * 8] = pp;   // same slot gl_lds16 would fill
                gl_lds16(J.Bm + (size_t)(n0 + row) * KD + kk + c * 8, Bs + p0 * 8);
            }
        } else {
            const bf_t* Ab = (const bf_t*)J.A;
#pragma unroll
            for (int it = 0; it < 4; ++it) {
                int p0 = it * 256 + wv * 64;
                int p = p0 + lane;
                int row = p >> 3;
                int c = (p & 7) ^ (row & 7);
                gl_lds16(Ab + (size_t)(m0 + row) * KD + kk + c * 8, As + p0 * 8);
                gl_lds16(J.Bm + (size_t)(n0 + row) * KD + kk + c * 8, Bs + p0 * 8);
            }
        }
        __syncthreads();
#pragma unroll
        for (int ks = 0; ks < 2; ++ks) {
            short8 a[4], b[4];
#pragma unroll
            for (int i = 0; i < 4; ++i) {
                int row = wm * 64 + i * 16 + l16;
                int pc = (ks * 4 + quad) ^ (row & 7);
                a[i] = *(const short8*)&As[row * 64 + pc * 8];
            }
#pragma unroll
            for (int j = 0; j < 4; ++j) {
                int row = wn * 64 + j * 16 + l16;
                int pc = (ks * 4 + quad) ^ (row & 7);
                b[j] = *(const short8*)&Bs[row * 64 + pc * 8];
            }
#pragma unroll
            for (int i = 0; i < 4; ++i)
#pragma unroll
                for (int j = 0; j < 4; ++j)
                    acc[i][j] = __builtin_amdgcn_mfma_f32_16x16x32_bf16(a[i], b[j], acc[i][j], 0, 0, 0);
        }
        __syncthreads();
    }

#pragma unroll
    for (int i = 0; i < 4; ++i) {
#pragma unroll
        for (int j = 0; j < 4; ++j) {
            int grow = m0 + wm * 64 + i * 16 + quad * 4;
            int gcol = n0 + wn * 64 + j * 16 + l16;
            if (J.mode == 0) {
                float bv = J.bias[gcol];
                int h = gcol >> 6, hd = gcol & 63;
                bf_t* dst = (bf_t*)J.out;
#pragma unroll
                for (int r = 0; r < 4; ++r) {
                    int row = grow + r;
                    int bI = row >> 12, s = row & 4095;
                    dst[(((size_t)(bI * Hh + h) * Sq + s) << 6) + hd] =
                        f2bf((acc[i][j][r] + bv) * J.scale);
                }
            } else if (J.mode == 3) {
                // K fragment-packed: [bh][kt][t=2g+s2][h2][lane][8]
                float bv = J.bias[gcol];
                int hh = gcol >> 6, hd = gcol & 63;
                int h2 = hd >> 5, rem = hd & 31, qd = rem >> 3, j2 = rem & 7;
                bf_t* dst = (bf_t*)J.out;
#pragma unroll
                for (int r = 0; r < 4; ++r) {
                    int row = grow + r;
                    int bI = row >> 12, s = row & 4095;
                    int kt2 = s >> 6, rr = s & 63;
                    int g2 = rr >> 5, r5 = rr & 31;
                    int a2 = r5 >> 3, s22 = (r5 >> 2) & 1, b2 = r5 & 3;
                    int lane2 = qd * 16 + (4 * a2 + b2);
                    dst[(size_t)(bI * Hh + hh) * Sq * 64 +
                        kt2 * 4096 + (2 * g2 + s22) * 1024 + h2 * 512 + lane2 * 8 + j2] =
                        f2bf(acc[i][j][r] + bv);
                }
            } else if (J.mode == 4) {
                // V fragment-packed from (token,feat) orientation:
                // token = grow+r -> key decomposition; feat = gcol -> ot/l16.
                // Same destination slot per (token,feat) as R11-verified mode 1.
                float bv = J.bias[gcol];
                int hh = gcol >> 6, hd = gcol & 63;
                int ot = hd >> 4, l16v = hd & 15;
                bf_t* dst = (bf_t*)J.out;
#pragma unroll
                for (int r = 0; r < 4; ++r) {
                    int row = grow + r;
                    int bI = row >> 12, s = row & 4095;
                    int kt2 = s >> 6, rr = s & 63;
                    int g2 = rr >> 5, qd = (rr & 31) >> 3, j2 = rr & 7;
                    int lane2 = qd * 16 + l16v;
                    dst[(size_t)(bI * Hh + hh) * Sq * 64 +
                        kt2 * 4096 + (g2 * 4 + ot) * 512 + lane2 * 8 + j2] =
                        f2bf(acc[i][j][r] + bv);
                }
            } else {
                float bv = J.bias[gcol];
                float* dst = (float*)J.out;
#pragma unroll
                for (int r = 0; r < 4; ++r)
                    dst[(size_t)(grow + r) * Dm + gcol] = acc[i][j][r] + bv;
            }
        }
    }
}

// ---------------- flash attention, causal, fixed-shift softmax ----------------
// R11-EXACT (best measured: 139 µs; frozen — R12's balanced-pair regressed).
// Q: [B*H, S, 64] bf16 (pre-scaled). K/VT: FRAGMENT-PACKED (gemm modes 3/4).
// 64 q-rows/wave (NQ=4), block = 4 waves {row-group x key-split}, private
// coalesced K/V loads with WAR prefetch, fixed-shift partials combined by
// pure addition via LDS. XCD swizzle. NOTE: no min-occupancy arg in
// __launch_bounds__ (R3: (256,4) forced 64-VGPR cap -> 2.3GB scratch spill).
#define SHIFT 18.0f
#define NQ 4

__global__ __launch_bounds__(256) void attn(const bf_t* __restrict__ Q,
                                            const bf_t* __restrict__ K,
                                            const bf_t* __restrict__ VT,
                                            bf_t* __restrict__ O) {
    const int id = blockIdx.x + 24 * blockIdx.y;
    const int xcd = id & 7, slot = id >> 3;        // slot 0..95
    const int bh = xcd * 3 + slot % 3;
    const int qt = 31 - slot / 3;                  // long blocks first
    const int lane = threadIdx.x & 63, wv = threadIdx.x >> 6;   // wv 0..3
    const int rg = wv & 1, ksp = wv >> 1;          // row-group, key-split
    const int l16 = lane & 15, quad = lane >> 4;
    const int b = bh / Hh, h = bh % Hh;
    const size_t base = (size_t)bh * Sq * 64;
    const int q0 = qt * 128 + rg * 64;             // 64 rows per wave

    __shared__ float ocomb[2][64][68];             // [rg][row][feat] fp32, padded
    __shared__ float lcomb[2][64];

    const bf_t* __restrict__ Kb = K + base;
    const bf_t* __restrict__ Vb = VT + base;

    // Q as B-frags (n=qrow l16, k=quad*8+j)
    short8 qf[NQ][2];
#pragma unroll
    for (int i = 0; i < NQ; ++i) {
        const bf_t* qp = Q + base + (size_t)(q0 + i * 16 + l16) * 64 + quad * 8;
        qf[i][0] = *(const short8*)qp;
        qf[i][1] = *(const short8*)(qp + 32);
    }

    f32x4 oacc[NQ][4] = {};   // O^T: [i][feat quad*4+r] x [qrow l16]
    f32x4 lsum[NQ] = {};

    const int nkt = (q0 >> 6) + 1;
    const int hsp = (nkt + 1) >> 1;
    const int kt0 = ksp ? hsp : 0;
    const int kt1 = ksp ? nkt : hsp;

    short8 ones32;
#pragma unroll
    for (int j = 0; j < 8; ++j) ones32[j] = (short)0x3F80;

    short8 kf[4][2];   // K frags (packed layout), t=2g+s
    short8 vfr[4][2];  // V frags [ot][g]

    // coalesced element offsets: lane*8 within each 512-elem packed group
    int ko = kt0 * 4096 + lane * 8;
    int vo = kt0 * 4096 + lane * 8;

#define LOAD_K()                                                             \
    {                                                                        \
        _Pragma("unroll")                                                    \
        for (int t = 0; t < 4; ++t) {                                        \
            kf[t][0] = *(const short8*)(Kb + ko + t * 1024);                 \
            kf[t][1] = *(const short8*)(Kb + ko + t * 1024 + 512);           \
        }                                                                    \
    }
#define LOAD_V()                                                             \
    {                                                                        \
        _Pragma("unroll")                                                    \
        for (int ot = 0; ot < 4; ++ot)                                       \
            _Pragma("unroll")                                                \
            for (int g = 0; g < 2; ++g)                                      \
                vfr[ot][g] = *(const short8*)(Vb + vo + (g * 4 + ot) * 512); \
    }

    if (kt0 < kt1) { LOAD_K(); LOAD_V(); }

    for (int kt = kt0; kt < kt1; ++kt) {
        const int kv0 = kt * 64;
        const bool more = (kt + 1 < kt1);
#pragma unroll
        for (int i = 0; i < NQ; ++i) {
            // QK: S^T tiles, permuted key order; C-init carries the -SHIFT
            f32x4 st[4];
#pragma unroll
            for (int t = 0; t < 4; ++t) {
                f32x4 z = {-SHIFT, -SHIFT, -SHIFT, -SHIFT};
                z = __builtin_amdgcn_mfma_f32_16x16x32_bf16(kf[t][0], qf[i][0], z, 0, 0, 0);
                st[t] = __builtin_amdgcn_mfma_f32_16x16x32_bf16(kf[t][1], qf[i][1], z, 0, 0, 0);
            }
            if (i == NQ - 1) { ko += 4096; if (more) LOAD_K(); }   // WAR prefetch

            // mask + exp2 + pack (permuted key = kv0+32g+8*quad+4s+r)
            alignas(16) unsigned int pkd[4][2];
            const bool need_mask = (kv0 + 63 > q0 + i * 16);
#pragma unroll
            for (int t = 0; t < 4; ++t) {
                int g = t >> 1, s = t & 1;
                f32x4 sv = st[t];
                if (need_mask) {
                    int qrow = q0 + i * 16 + l16;
                    int kb2 = kv0 + 32 * g + 8 * quad + 4 * s;
#pragma unroll
                    for (int r = 0; r < 4; ++r)
                        if (kb2 + r > qrow) sv[r] = -1e30f;
                }
                pkd[t][0] = pk2bf(fexp2(sv[0]), fexp2(sv[1]));
                pkd[t][1] = pk2bf(fexp2(sv[2]), fexp2(sv[3]));
            }
            // PV: B-frag direct from pkd, K=32
#pragma unroll
            for (int g = 0; g < 2; ++g) {
                short8 pf = *(const short8*)&pkd[2 * g][0];
                lsum[i] = __builtin_amdgcn_mfma_f32_16x16x32_bf16(ones32, pf, lsum[i], 0, 0, 0);
#pragma unroll
                for (int ot = 0; ot < 4; ++ot)
                    oacc[i][ot] = __builtin_amdgcn_mfma_f32_16x16x32_bf16(vfr[ot][g], pf, oacc[i][ot], 0, 0, 0);
            }
        }
        vo += 4096;
        if (more) LOAD_V();   // WAR prefetch
    }
#undef LOAD_K
#undef LOAD_V

    // combine partials: split-1 writes, barrier, split-0 adds + epilogue
    if (ksp) {
#pragma unroll
        for (int i = 0; i < NQ; ++i) {
            int row = i * 16 + l16;
#pragma unroll
            for (int ot = 0; ot < 4; ++ot)
                *(f32x4*)&ocomb[rg][row][ot * 16 + quad * 4] = oacc[i][ot];
            if (quad == 0) lcomb[rg][row] = lsum[i][0];
        }
    }
    __syncthreads();
    if (!ksp) {
#pragma unroll
        for (int i = 0; i < NQ; ++i) {
            int row = i * 16 + l16;
            float ls = lsum[i][0] + lcomb[rg][row];
            float inv = 1.0f / ls;
            int srow = q0 + row;
            bf_t* orow = O + (size_t)(b * Sq + srow) * Dm + h * 64;
#pragma unroll
            for (int ot = 0; ot < 4; ++ot) {
                f32x4 oc = *(const f32x4*)&ocomb[rg][row][ot * 16 + quad * 4];
                uint2 pk;
                pk.x = pk2bf((oacc[i][ot][0] + oc[0]) * inv, (oacc[i][ot][1] + oc[1]) * inv);
                pk.y = pk2bf((oacc[i][ot][2] + oc[2]) * inv, (oacc[i][ot][3] + oc[3]) * inv);
                *(uint2*)(orow + ot * 16 + quad * 4) = pk;
            }
        }
    }
}

extern "C" void kernel_launch(void* const* d_in, const int* in_sizes, int n_in,
                              void* d_out, int out_size, void* d_ws, size_t ws_size,
                              hipStream_t stream) {
    const float* q  = (const float*)d_in[0];
    const float* k  = (const float*)d_in[1];
    const float* v  = (const float*)d_in[2];
    // d_in[3]: causal mask — analytic
    const float* Wq = (const float*)d_in[4];  const float* bq = (const float*)d_in[5];
    const float* Wk = (const float*)d_in[6];  const float* bk = (const float*)d_in[7];
    const float* Wv = (const float*)d_in[8];  const float* bv = (const float*)d_in[9];
    const float* Wo = (const float*)d_in[10]; const float* bo = (const float*)d_in[11];
    float* out = (float*)d_out;

    const float QSCALE = 0.125f * 1.44269504f;     // (1/sqrt(64)) * log2(e)

    const size_t NTOK = (size_t)2 * Sq * Dm;   // 6291456
    const size_t NW   = (size_t)Dm * Dm;       // 589824
    dim3 b256(256);

    // workspace: qb, kb, vb, ob (bf16 NTOK each) + 4 weights (bf16 NW each)
    // = 55.2 MB (less than the previous 80.2 MB requirement, which was met)
    bf_t* qb  = (bf_t*)d_ws;
    bf_t* kb  = qb + NTOK;
    bf_t* vb  = kb + NTOK;
    bf_t* ob  = vb + NTOK;
    bf_t* wqb = ob + NTOK;
    bf_t* wkb = wqb + NW;
    bf_t* wvb = wkb + NW;
    bf_t* wob = wvb + NW;

    // weights-only cvt (input conversion fused into GEMM staging)
    CvtJobs cw = {{Wq, Wk, Wv, Wo, Wq, Wq, Wq, Wq},
                  {wqb, wkb, wvb, wob, wqb, wqb, wqb, wqb},
                  {(int)NW, (int)NW, (int)NW, (int)NW, 0, 0, 0, 0}};
    cvt<<<dim3(288, 1, 4), b256, 0, stream>>>(cw);

    GemmJobs gp;
    gp.j[0] = {q, wqb, bq, qb, 0, QSCALE, 1};
    gp.j[1] = {k, wkb, bk, kb, 3, 1.0f, 1};    // K fragment-packed
    gp.j[2] = {v, wvb, bv, vb, 4, 1.0f, 1};    // V fragment-packed (A=tokens)
    gemm_k<<<dim3(64, 6, 3), b256, 0, stream>>>(gp);

    attn<<<dim3(2 * Hh, Sq / 128), b256, 0, stream>>>(qb, kb, vb, ob);

    GemmJobs go;
    go.j[0] = {ob, wob, bo, out, 2, 1.0f, 0};
    go.j[1] = go.j[0]; go.j[2] = go.j[0];
    gemm_k<<<dim3(64, 6, 1), b256, 0, stream>>>(go);
}

// Round 14
// 341.490 us; speedup vs baseline: 1.1217x; 1.0507x over previous
//
#include <hip/hip_runtime.h>

// B=2, S=4096, D=768, H=12, HD=64
#define Sq 4096
#define Dm 768
#define Hh 12
#define KD 768

typedef short short8 __attribute__((ext_vector_type(8)));
typedef float f32x4 __attribute__((ext_vector_type(4)));
typedef unsigned short bf_t;

__device__ inline bf_t f2bf(float f) {
    unsigned int u = __builtin_bit_cast(unsigned int, f);
    u += 0x7fffu + ((u >> 16) & 1u);   // RNE
    return (bf_t)(u >> 16);
}

// pack two fp32 -> bf16x2 (round-half-up: 1 add each + 1 v_perm) — HW-verified path
__device__ inline unsigned int pk2bf(float a, float b) {
    unsigned int ua = __builtin_bit_cast(unsigned int, a) + 0x8000u;
    unsigned int ub = __builtin_bit_cast(unsigned int, b) + 0x8000u;
    return __builtin_amdgcn_perm(ub, ua, 0x07060302);
}

__device__ inline float fexp2(float x) {
#if __has_builtin(__builtin_amdgcn_exp2f)
    return __builtin_amdgcn_exp2f(x);
#else
    return exp2f(x);
#endif
}

__device__ inline void gl_lds16(const void* g, void* l) {
    __builtin_amdgcn_global_load_lds(
        (const __attribute__((address_space(1))) unsigned int*)g,
        (__attribute__((address_space(3))) unsigned int*)l, 16, 0, 0);
}

// ---------------- fp32 -> bf16 convert (weights only) ----------------
struct CvtJobs { const float* s[8]; bf_t* d[8]; int n[8]; };

__global__ __launch_bounds__(256) void cvt(CvtJobs jobs) {
    const float* s = jobs.s[blockIdx.z];
    bf_t* d = jobs.d[blockIdx.z];
    int n = jobs.n[blockIdx.z];
    int i = (blockIdx.x * 256 + threadIdx.x) * 8;
    if (i < n) {
        float4 a = *(const float4*)(s + i);
        float4 b = *(const float4*)(s + i + 4);
        short8 p;
        p[0] = (short)f2bf(a.x); p[1] = (short)f2bf(a.y);
        p[2] = (short)f2bf(a.z); p[3] = (short)f2bf(a.w);
        p[4] = (short)f2bf(b.x); p[5] = (short)f2bf(b.y);
        p[6] = (short)f2bf(b.z); p[7] = (short)f2bf(b.w);
        *(short8*)(d + i) = p;
    }
}

// ---------------- bf16 GEMM: C = A (MxK) * B^T (NxK) + bias ----------------
// Template A32=1: A is fp32 — conversion fused into staging, PIPELINED:
//   loads for kk+1 issue AFTER the first barrier (not drained by it) and
//   land during the MFMA phase (R14; R13's serial wait-then-convert cost
//   ~1 exposed HBM latency per K-step).
// mode 0: Q -> standard [bh][s][64] (scaled)
// mode 3: K -> FRAGMENT-PACKED [bh][kt][t][half][lane][8]
// mode 4: V -> FRAGMENT-PACKED [bh][kt][g*4+ot][lane][8] (A=tokens)
// mode 2: fp32 out [row][Dm]
struct GemmJob {
    const void* __restrict__ A; const bf_t* __restrict__ Bm;
    const float* __restrict__ bias; void* __restrict__ out;
    int mode; float scale;
};
struct GemmJobs { GemmJob j[3]; };

template <int A32>
__global__ __launch_bounds__(256) void gemm_k(GemmJobs jobs) {
    const GemmJob J = jobs.j[blockIdx.z];
    __shared__ bf_t As[128 * 64];
    __shared__ bf_t Bs[128 * 64];
    const int lane = threadIdx.x & 63, wv = threadIdx.x >> 6;
    const int l16 = lane & 15, quad = lane >> 4;
    const int wm = wv >> 1, wn = wv & 1;
    const int m0 = blockIdx.x * 128, n0 = blockIdx.y * 128;

    f32x4 acc[4][4] = {};

    float4 ra[4][2];   // A32 pipeline regs (dead when A32=0)
#define LOADA(KK)                                                            \
    {                                                                        \
        const float* A32p = (const float*)J.A;                               \
        _Pragma("unroll")                                                    \
        for (int it = 0; it < 4; ++it) {                                     \
            int p = it * 256 + wv * 64 + lane;                               \
            int row = p >> 3;                                                \
            int c = (p & 7) ^ (row & 7);                                     \
            const float* src = A32p + (size_t)(m0 + row) * KD + (KK) + c * 8;\
            ra[it][0] = *(const float4*)src;                                 \
            ra[it][1] = *(const float4*)(src + 4);                           \
        }                                                                    \
    }

    if (A32) LOADA(0);

    for (int kk = 0; kk < KD; kk += 64) {
        if (A32) {
#pragma unroll
            for (int it = 0; it < 4; ++it) {
                int p0 = it * 256 + wv * 64;
                int p = p0 + lane;
                int row = p >> 3;
                int c = (p & 7) ^ (row & 7);
                short8 pp;
                pp[0] = (short)f2bf(ra[it][0].x); pp[1] = (short)f2bf(ra[it][0].y);
                pp[2] = (short)f2bf(ra[it][0].z); pp[3] = (short)f2bf(ra[it][0].w);
                pp[4] = (short)f2bf(ra[it][1].x); pp[5] = (short)f2bf(ra[it][1].y);
                pp[6] = (short)f2bf(ra[it][1].z); pp[7] = (short)f2bf(ra[it][1].w);
                *(short8*)&As[p * 8] = pp;
                gl_lds16(J.Bm + (size_t)(n0 + row) * KD + kk + c * 8, Bs + p0 * 8);
            }
        } else {
            const bf_t* Ab = (const bf_t*)J.A;
#pragma unroll
            for (int it = 0; it < 4; ++it) {
                int p0 = it * 256 + wv * 64;
                int p = p0 + lane;
                int row = p >> 3;
                int c = (p & 7) ^ (row & 7);
                gl_lds16(Ab + (size_t)(m0 + row) * KD + kk + c * 8, As + p0 * 8);
                gl_lds16(J.Bm + (size_t)(n0 + row) * KD + kk + c * 8, Bs + p0 * 8);
            }
        }
        __syncthreads();
        if (A32 && kk + 64 < KD) LOADA(kk + 64);   // in flight during compute
#pragma unroll
        for (int ks = 0; ks < 2; ++ks) {
            short8 a[4], b[4];
#pragma unroll
            for (int i = 0; i < 4; ++i) {
                int row = wm * 64 + i * 16 + l16;
                int pc = (ks * 4 + quad) ^ (row & 7);
                a[i] = *(const short8*)&As[row * 64 + pc * 8];
            }
#pragma unroll
            for (int j = 0; j < 4; ++j) {
                int row = wn * 64 + j * 16 + l16;
                int pc = (ks * 4 + quad) ^ (row & 7);
                b[j] = *(const short8*)&Bs[row * 64 + pc * 8];
            }
#pragma unroll
            for (int i = 0; i < 4; ++i)
#pragma unroll
                for (int j = 0; j < 4; ++j)
                    acc[i][j] = __builtin_amdgcn_mfma_f32_16x16x32_bf16(a[i], b[j], acc[i][j], 0, 0, 0);
        }
        __syncthreads();
    }
#undef LOADA

#pragma unroll
    for (int i = 0; i < 4; ++i) {
#pragma unroll
        for (int j = 0; j < 4; ++j) {
            int grow = m0 + wm * 64 + i * 16 + quad * 4;
            int gcol = n0 + wn * 64 + j * 16 + l16;
            if (J.mode == 0) {
                float bv = J.bias[gcol];
                int h = gcol >> 6, hd = gcol & 63;
                bf_t* dst = (bf_t*)J.out;
#pragma unroll
                for (int r = 0; r < 4; ++r) {
                    int row = grow + r;
                    int bI = row >> 12, s = row & 4095;
                    dst[(((size_t)(bI * Hh + h) * Sq + s) << 6) + hd] =
                        f2bf((acc[i][j][r] + bv) * J.scale);
                }
            } else if (J.mode == 3) {
                // K fragment-packed: [bh][kt][t=2g+s2][h2][lane][8]
                float bv = J.bias[gcol];
                int hh = gcol >> 6, hd = gcol & 63;
                int h2 = hd >> 5, rem = hd & 31, qd = rem >> 3, j2 = rem & 7;
                bf_t* dst = (bf_t*)J.out;
#pragma unroll
                for (int r = 0; r < 4; ++r) {
                    int row = grow + r;
                    int bI = row >> 12, s = row & 4095;
                    int kt2 = s >> 6, rr = s & 63;
                    int g2 = rr >> 5, r5 = rr & 31;
                    int a2 = r5 >> 3, s22 = (r5 >> 2) & 1, b2 = r5 & 3;
                    int lane2 = qd * 16 + (4 * a2 + b2);
                    dst[(size_t)(bI * Hh + hh) * Sq * 64 +
                        kt2 * 4096 + (2 * g2 + s22) * 1024 + h2 * 512 + lane2 * 8 + j2] =
                        f2bf(acc[i][j][r] + bv);
                }
            } else if (J.mode == 4) {
                // V fragment-packed from (token,feat) orientation
                float bv = J.bias[gcol];
                int hh = gcol >> 6, hd = gcol & 63;
                int ot = hd >> 4, l16v = hd & 15;
                bf_t* dst = (bf_t*)J.out;
#pragma unroll
                for (int r = 0; r < 4; ++r) {
                    int row = grow + r;
                    int bI = row >> 12, s = row & 4095;
                    int kt2 = s >> 6, rr = s & 63;
                    int g2 = rr >> 5, qd = (rr & 31) >> 3, j2 = rr & 7;
                    int lane2 = qd * 16 + l16v;
                    dst[(size_t)(bI * Hh + hh) * Sq * 64 +
                        kt2 * 4096 + (g2 * 4 + ot) * 512 + lane2 * 8 + j2] =
                        f2bf(acc[i][j][r] + bv);
                }
            } else {
                float bv = J.bias[gcol];
                float* dst = (float*)J.out;
#pragma unroll
                for (int r = 0; r < 4; ++r)
                    dst[(size_t)(grow + r) * Dm + gcol] = acc[i][j][r] + bv;
            }
        }
    }
}

// ---------------- flash attention, causal, fixed-shift softmax ----------------
// R11/R13 structure + 2-DEEP K/V REGISTER PREFETCH (R14): LOAD(kt+2) issues
// during tile kt -> a full tile (~1200cyc) of compute covers the ~900cyc load
// latency that the 1-deep WAR prefetch left ~600cyc exposed per tile (the
// last uncharacterized stall; all other levers tested null R4-R12).
// Static double-buffer (named A/B, no runtime indexing - scratch rule).
// Q: [B*H,S,64] bf16 (pre-scaled). K/VT: FRAGMENT-PACKED (gemm modes 3/4).
// 64 q-rows/wave (NQ=4), block = 4 waves {row-group x key-split}, fixed-shift
// partials combined by pure addition via LDS. XCD swizzle. NOTE: no
// min-occupancy arg in __launch_bounds__ (R3: forced cap -> scratch spill).
#define SHIFT 18.0f
#define NQ 4

__global__ __launch_bounds__(256) void attn(const bf_t* __restrict__ Q,
                                            const bf_t* __restrict__ K,
                                            const bf_t* __restrict__ VT,
                                            bf_t* __restrict__ O) {
    const int id = blockIdx.x + 24 * blockIdx.y;
    const int xcd = id & 7, slot = id >> 3;        // slot 0..95
    const int bh = xcd * 3 + slot % 3;
    const int qt = 31 - slot / 3;                  // long blocks first
    const int lane = threadIdx.x & 63, wv = threadIdx.x >> 6;   // wv 0..3
    const int rg = wv & 1, ksp = wv >> 1;          // row-group, key-split
    const int l16 = lane & 15, quad = lane >> 4;
    const int b = bh / Hh, h = bh % Hh;
    const size_t base = (size_t)bh * Sq * 64;
    const int q0 = qt * 128 + rg * 64;             // 64 rows per wave

    __shared__ float ocomb[2][64][68];             // [rg][row][feat] fp32, padded
    __shared__ float lcomb[2][64];

    const bf_t* __restrict__ Kb = K + base;
    const bf_t* __restrict__ Vb = VT + base;

    // Q as B-frags (n=qrow l16, k=quad*8+j)
    short8 qf[NQ][2];
#pragma unroll
    for (int i = 0; i < NQ; ++i) {
        const bf_t* qp = Q + base + (size_t)(q0 + i * 16 + l16) * 64 + quad * 8;
        qf[i][0] = *(const short8*)qp;
        qf[i][1] = *(const short8*)(qp + 32);
    }

    f32x4 oacc[NQ][4] = {};   // O^T: [i][feat quad*4+r] x [qrow l16]
    f32x4 lsum[NQ] = {};

    const int nkt = (q0 >> 6) + 1;
    const int hsp = (nkt + 1) >> 1;
    const int kt0 = ksp ? hsp : 0;
    const int kt1 = ksp ? nkt : hsp;

    short8 ones32;
#pragma unroll
    for (int j = 0; j < 8; ++j) ones32[j] = (short)0x3F80;

    short8 kfA[4][2], vfrA[4][2];   // double-buffered K/V frags
    short8 kfB[4][2], vfrB[4][2];

#define LOAD_KF(KF, KT)                                                      \
    {                                                                        \
        int o = (KT) * 4096 + lane * 8;                                      \
        _Pragma("unroll")                                                    \
        for (int t = 0; t < 4; ++t) {                                        \
            KF[t][0] = *(const short8*)(Kb + o + t * 1024);                  \
            KF[t][1] = *(const short8*)(Kb + o + t * 1024 + 512);            \
        }                                                                    \
    }
#define LOAD_VF(VF, KT)                                                      \
    {                                                                        \
        int o = (KT) * 4096 + lane * 8;                                      \
        _Pragma("unroll")                                                    \
        for (int ot = 0; ot < 4; ++ot)                                       \
            _Pragma("unroll")                                                \
            for (int g = 0; g < 2; ++g)                                      \
                VF[ot][g] = *(const short8*)(Vb + o + (g * 4 + ot) * 512);   \
    }

// one K-tile: QK (with kt+2 K-prefetch into own buffer), mask/exp, PV,
// then kt+2 V-prefetch. Register contents identical to the verified R11 body.
#define TILE_BODY(KF, VF, KT)                                                \
    {                                                                        \
        const int kv0 = (KT) * 64;                                           \
        _Pragma("unroll")                                                    \
        for (int i = 0; i < NQ; ++i) {                                       \
            f32x4 st[4];                                                     \
            _Pragma("unroll")                                                \
            for (int t = 0; t < 4; ++t) {                                    \
                f32x4 z = {-SHIFT, -SHIFT, -SHIFT, -SHIFT};                  \
                z = __builtin_amdgcn_mfma_f32_16x16x32_bf16(KF[t][0], qf[i][0], z, 0, 0, 0); \
                st[t] = __builtin_amdgcn_mfma_f32_16x16x32_bf16(KF[t][1], qf[i][1], z, 0, 0, 0); \
            }                                                                \
            if (i == NQ - 1 && (KT) + 2 < kt1) LOAD_KF(KF, (KT) + 2);        \
            alignas(16) unsigned int pkd[4][2];                              \
            const bool need_mask = (kv0 + 63 > q0 + i * 16);                 \
            _Pragma("unroll")                                                \
            for (int t = 0; t < 4; ++t) {                                    \
                int g = t >> 1, s = t & 1;                                   \
                f32x4 sv = st[t];                                            \
                if (need_mask) {                                             \
                    int qrow = q0 + i * 16 + l16;                            \
                    int kb2 = kv0 + 32 * g + 8 * quad + 4 * s;               \
                    _Pragma("unroll")                                        \
                    for (int r = 0; r < 4; ++r)                              \
                        if (kb2 + r > qrow) sv[r] = -1e30f;                  \
                }                                                            \
                pkd[t][0] = pk2bf(fexp2(sv[0]), fexp2(sv[1]));               \
                pkd[t][1] = pk2bf(fexp2(sv[2]), fexp2(sv[3]));               \
            }                                                                \
            _Pragma("unroll")                                                \
            for (int g = 0; g < 2; ++g) {                                    \
                short8 pf = *(const short8*)&pkd[2 * g][0];                  \
                lsum[i] = __builtin_amdgcn_mfma_f32_16x16x32_bf16(ones32, pf, lsum[i], 0, 0, 0); \
                _Pragma("unroll")                                            \
                for (int ot = 0; ot < 4; ++ot)                               \
                    oacc[i][ot] = __builtin_amdgcn_mfma_f32_16x16x32_bf16(VF[ot][g], pf, oacc[i][ot], 0, 0, 0); \
            }                                                                \
        }                                                                    \
        if ((KT) + 2 < kt1) LOAD_VF(VF, (KT) + 2);                           \
    }

    if (kt0 < kt1)     { LOAD_KF(kfA, kt0);     LOAD_VF(vfrA, kt0); }
    if (kt0 + 1 < kt1) { LOAD_KF(kfB, kt0 + 1); LOAD_VF(vfrB, kt0 + 1); }

    for (int kt = kt0; kt < kt1; kt += 2) {
        TILE_BODY(kfA, vfrA, kt);
        if (kt + 1 < kt1) TILE_BODY(kfB, vfrB, kt + 1);
    }
#undef LOAD_KF
#undef LOAD_VF
#undef TILE_BODY

    // combine partials: split-1 writes, barrier, split-0 adds + epilogue
    if (ksp) {
#pragma unroll
        for (int i = 0; i < NQ; ++i) {
            int row = i * 16 + l16;
#pragma unroll
            for (int ot = 0; ot < 4; ++ot)
                *(f32x4*)&ocomb[rg][row][ot * 16 + quad * 4] = oacc[i][ot];
            if (quad == 0) lcomb[rg][row] = lsum[i][0];
        }
    }
    __syncthreads();
    if (!ksp) {
#pragma unroll
        for (int i = 0; i < NQ; ++i) {
            int row = i * 16 + l16;
            float ls = lsum[i][0] + lcomb[rg][row];
            float inv = 1.0f / ls;
            int srow = q0 + row;
            bf_t* orow = O + (size_t)(b * Sq + srow) * Dm + h * 64;
#pragma unroll
            for (int ot = 0; ot < 4; ++ot) {
                f32x4 oc = *(const f32x4*)&ocomb[rg][row][ot * 16 + quad * 4];
                uint2 pk;
                pk.x = pk2bf((oacc[i][ot][0] + oc[0]) * inv, (oacc[i][ot][1] + oc[1]) * inv);
                pk.y = pk2bf((oacc[i][ot][2] + oc[2]) * inv, (oacc[i][ot][3] + oc[3]) * inv);
                *(uint2*)(orow + ot * 16 + quad * 4) = pk;
            }
        }
    }
}

extern "C" void kernel_launch(void* const* d_in, const int* in_sizes, int n_in,
                              void* d_out, int out_size, void* d_ws, size_t ws_size,
                              hipStream_t stream) {
    const float* q  = (const float*)d_in[0];
    const float* k  = (const float*)d_in[1];
    const float* v  = (const float*)d_in[2];
    // d_in[3]: causal mask — analytic
    const float* Wq = (const float*)d_in[4];  const float* bq = (const float*)d_in[5];
    const float* Wk = (const float*)d_in[6];  const float* bk = (const float*)d_in[7];
    const float* Wv = (const float*)d_in[8];  const float* bv = (const float*)d_in[9];
    const float* Wo = (const float*)d_in[10]; const float* bo = (const float*)d_in[11];
    float* out = (float*)d_out;

    const float QSCALE = 0.125f * 1.44269504f;     // (1/sqrt(64)) * log2(e)

    const size_t NTOK = (size_t)2 * Sq * Dm;   // 6291456
    const size_t NW   = (size_t)Dm * Dm;       // 589824
    dim3 b256(256);

    // workspace: qb, kb, vb, ob (bf16 NTOK each) + 4 weights (bf16 NW each)
    bf_t* qb  = (bf_t*)d_ws;
    bf_t* kb  = qb + NTOK;
    bf_t* vb  = kb + NTOK;
    bf_t* ob  = vb + NTOK;
    bf_t* wqb = ob + NTOK;
    bf_t* wkb = wqb + NW;
    bf_t* wvb = wkb + NW;
    bf_t* wob = wvb + NW;

    // weights-only cvt (input conversion fused into GEMM staging)
    CvtJobs cw = {{Wq, Wk, Wv, Wo, Wq, Wq, Wq, Wq},
                  {wqb, wkb, wvb, wob, wqb, wqb, wqb, wqb},
                  {(int)NW, (int)NW, (int)NW, (int)NW, 0, 0, 0, 0}};
    cvt<<<dim3(288, 1, 4), b256, 0, stream>>>(cw);

    GemmJobs gp;
    gp.j[0] = {q, wqb, bq, qb, 0, QSCALE};
    gp.j[1] = {k, wkb, bk, kb, 3, 1.0f};    // K fragment-packed
    gp.j[2] = {v, wvb, bv, vb, 4, 1.0f};    // V fragment-packed (A=tokens)
    gemm_k<1><<<dim3(64, 6, 3), b256, 0, stream>>>(gp);

    attn<<<dim3(2 * Hh, Sq / 128), b256, 0, stream>>>(qb, kb, vb, ob);

    GemmJobs go;
    go.j[0] = {ob, wob, bo, out, 2, 1.0f};
    go.j[1] = go.j[0]; go.j[2] = go.j[0];
    gemm_k<0><<<dim3(64, 6, 1), b256, 0, stream>>>(go);
}